// Round 12
// baseline (37.565 us; speedup 1.0000x reference)
//
#include <hip/hip_runtime.h>
#include <hip/hip_bf16.h>

// DecoderBlock: block-sparse masked linear (8 GEMMs M=256,N=1024,K=1024)
// + BatchNorm1d (batch stats; bias cancels exactly) + Swish.
// Round-12 = Round-11 with the A-buffer race fixed: A issued 2 steps ahead
// REQUIRES a 3-deep LDS ring (st%3); 2-deep aliased the buffer being read.
// Block = 128 batch rows x 32 features; grid 512 = 8g x 2h x 32nt.
// LDS ~58KB -> 2 blocks/CU -> all 512 co-resident (spin-safe), 2 pipelines/CU.
// BN stats cross the (h=0,h=1) pair via device-scope atomics + release/acquire
// flag; exactly 2 addends per feature -> deterministic.

typedef float  f32x4  __attribute__((ext_vector_type(4)));
typedef short  short8 __attribute__((ext_vector_type(8)));
typedef unsigned short u16x8 __attribute__((ext_vector_type(8)));

static __device__ __forceinline__ unsigned short f2bf(float f) {
    unsigned int u = __float_as_uint(f);
    u += 0x7FFFu + ((u >> 16) & 1u);          // RNE (inputs finite)
    return (unsigned short)(u >> 16);
}

#define GLL(gp, lp) __builtin_amdgcn_global_load_lds( \
    (const __attribute__((address_space(1))) unsigned int*)(gp), \
    (__attribute__((address_space(3))) unsigned int*)(lp), 16, 0, 0)

// ---------------- x f32 -> bf16 (12 MB traffic; result L2/L3-resident) ----------------
__global__ __launch_bounds__(256) void conv_kernel(const float* __restrict__ x,
                                                   unsigned short* __restrict__ xb) {
    const int base = blockIdx.x * 1024 + threadIdx.x;
#pragma unroll
    for (int i = 0; i < 4; ++i) {
        const int cid = base + i * 256;               // 8-float chunk id
        const f32x4 a = *(const f32x4*)(x + (size_t)cid * 8);
        const f32x4 b = *(const f32x4*)(x + (size_t)cid * 8 + 4);
        u16x8 v;
        v[0] = f2bf(a[0]); v[1] = f2bf(a[1]); v[2] = f2bf(a[2]); v[3] = f2bf(a[3]);
        v[4] = f2bf(b[0]); v[5] = f2bf(b[1]); v[6] = f2bf(b[2]); v[7] = f2bf(b[3]);
        *(u16x8*)(xb + (size_t)cid * 8) = v;
    }
}

// ---------------- fused half-batch GEMM + cross-pair BN + Swish ----------------
// Block: M=128 x N=32, K=1024, BK=64 (16 steps). 4 waves x 32 rows.
// A: [128][64] bf16 LDS x3 (GLL, src pre-swizzle c^=r&7), issued 2 steps ahead.
// W: f32 reg-ring depth 4, issued 3 ahead.
// vmcnt per iter: WRITEB(st+1) retires thru W(st+1) (in-order); then
// outstanding = A(st+1)4 + W(st+2)2 + A(st+2)4 + W(st+3)2 = 12 -> vmcnt(8)
// retires exactly A(st+1). Tail: vmcnt(6) at st=13, vmcnt(0) at st=14.
__global__ __launch_bounds__(256, 2) void fused_kernel(
    const unsigned short* __restrict__ xb, const float* __restrict__ W,
    const float* __restrict__ gamma, const float* __restrict__ beta,
    float* __restrict__ out, float* __restrict__ stats,
    unsigned int* __restrict__ flags)
{
    __shared__ __align__(16) char ldsA[3][16384];
    __shared__ __align__(16) char ldsB[2][4096];
    __shared__ float wps1[4][32], wps2[4][32];
    __shared__ float sa[32], sb[32];

    const int bid = blockIdx.x;
    const int g   = bid & 7;               // channel group -> XCD (round-robin)
    const int h   = (bid >> 3) & 1;        // batch half
    const int nt  = bid >> 4;              // 0..31
    const int o   = g * 4 + (nt >> 3);
    const int f0  = (nt & 7) * 32;
    const int gcol0 = o * 256 + f0;

    const int t    = threadIdx.x;
    const int wave = t >> 6;
    const int lane = t & 63;
    const int lr   = lane & 15;
    const int kq   = lane >> 4;

    f32x4 acc[2][2];
    const f32x4 zero = {0.f, 0.f, 0.f, 0.f};
#pragma unroll
    for (int i = 0; i < 2; ++i) { acc[i][0] = zero; acc[i][1] = zero; }

    f32x4 breg[4][2];                      // W prefetch ring, depth 4

    const unsigned short* xh = xb + (size_t)(h * 128) * 8192 + g * 1024;

    auto ISSUE_A = [&](int st) {           // 4 GLL (16B), source pre-swizzled
        const unsigned short* asrc = xh + st * 64;
        char* Ab = ldsA[st % 3];
#pragma unroll
        for (int i = 0; i < 4; ++i) {
            const int cid = i * 256 + t;            // 0..1023
            const int r = cid >> 3, c = cid & 7;    // row 0..127, chunk 0..7
            GLL(asrc + (size_t)r * 8192 + (c ^ (r & 7)) * 8, Ab + cid * 16);
        }
    };
    auto ISSUE_W = [&](int st) {           // 2 x 16B loads into ring slot st&3
        const int cp = st >> 2, kc = (st & 3) * 64;
        const float* bsrc = W + ((size_t)((o * 32 + g * 4 + cp) * 256 + f0)) * 256 + kc
                              + (size_t)(t >> 3) * 256 + (t & 7) * 8;
        breg[st & 3][0] = *(const f32x4*)bsrc;
        breg[st & 3][1] = *(const f32x4*)(bsrc + 4);
    };
    auto WRITEB = [&](int st) {            // cvt + swizzled ds_write (3-iter W lead)
        const int n = t >> 3, c = t & 7;
        short8 v;
        v[0] = (short)f2bf(breg[st & 3][0][0]); v[1] = (short)f2bf(breg[st & 3][0][1]);
        v[2] = (short)f2bf(breg[st & 3][0][2]); v[3] = (short)f2bf(breg[st & 3][0][3]);
        v[4] = (short)f2bf(breg[st & 3][1][0]); v[5] = (short)f2bf(breg[st & 3][1][1]);
        v[6] = (short)f2bf(breg[st & 3][1][2]); v[7] = (short)f2bf(breg[st & 3][1][3]);
        *(short8*)(ldsB[st & 1] + n * 128 + ((c ^ (n & 7)) * 16)) = v;
    };
    auto COMPUTE = [&](int st) {
        const char* Ab = ldsA[st % 3];
        const char* Bb = ldsB[st & 1];
#pragma unroll
        for (int ks = 0; ks < 2; ++ks) {
            short8 af[2], bfr[2];
#pragma unroll
            for (int i = 0; i < 2; ++i) {
                const int ra = wave * 32 + i * 16 + lr;        // 0..127
                af[i] = *(const short8*)(Ab + ra * 128 + (((ks * 4 + kq) ^ (ra & 7)) * 16));
            }
#pragma unroll
            for (int j = 0; j < 2; ++j) {
                const int n = j * 16 + lr;
                bfr[j] = *(const short8*)(Bb + n * 128 + (((ks * 4 + kq) ^ (n & 7)) * 16));
            }
#pragma unroll
            for (int i = 0; i < 2; ++i)
#pragma unroll
                for (int j = 0; j < 2; ++j)
                    acc[i][j] = __builtin_amdgcn_mfma_f32_16x16x32_bf16(af[i], bfr[j], acc[i][j], 0, 0, 0);
        }
    };

    // prologue: A(0),A(1),W(0..2); WRITEB(0) waits W(0) -> retires A(0),A(1).
    ISSUE_A(0);
    ISSUE_A(1);
    ISSUE_W(0);
    ISSUE_W(1);
    ISSUE_W(2);
    WRITEB(0);
    asm volatile("s_waitcnt lgkmcnt(0)" ::: "memory");
    __builtin_amdgcn_s_barrier();

#pragma unroll
    for (int st = 0; st < 16; ++st) {
        COMPUTE(st);                                   // reads A[st%3], B[st&1]
        if (st <= 13) ISSUE_A(st + 2);                 // writes A[(st+2)%3] (disjoint)
        if (st <= 12) ISSUE_W(st + 3);
        if (st <= 14) {
            WRITEB(st + 1);                            // waits W(st+1) only
            if (st <= 12) {
                asm volatile("s_waitcnt vmcnt(8)" ::: "memory");   // gate A(st+1)
            } else if (st == 13) {
                asm volatile("s_waitcnt vmcnt(6)" ::: "memory");   // gate A(14); A(15),W(15)? A(15)4+... = 6 left
            } else {
                asm volatile("s_waitcnt vmcnt(0)" ::: "memory");   // drain A(15)
            }
            asm volatile("s_waitcnt lgkmcnt(0)" ::: "memory");
            __builtin_amdgcn_s_barrier();
        }
    }

    // ---------------- BN: block-partial stats -> atomic pair-exchange ----------------
    float s1[2] = {0.f, 0.f}, s2[2] = {0.f, 0.f};
#pragma unroll
    for (int i = 0; i < 2; ++i)
#pragma unroll
        for (int j = 0; j < 2; ++j)
#pragma unroll
            for (int r = 0; r < 4; ++r) {
                const float v = acc[i][j][r];
                s1[j] += v; s2[j] += v * v;
            }
#pragma unroll
    for (int j = 0; j < 2; ++j) {          // reduce across kq groups (lanes sharing lr)
        s1[j] += __shfl_xor(s1[j], 16); s2[j] += __shfl_xor(s2[j], 16);
        s1[j] += __shfl_xor(s1[j], 32); s2[j] += __shfl_xor(s2[j], 32);
    }
    if (kq == 0) {
#pragma unroll
        for (int j = 0; j < 2; ++j) {
            wps1[wave][j * 16 + lr] = s1[j];
            wps2[wave][j * 16 + lr] = s2[j];
        }
    }
    __syncthreads();
    if (t < 32) {                          // 128-row partials -> device-scope atomics
        const float a1 = wps1[0][t] + wps1[1][t] + wps1[2][t] + wps1[3][t];
        const float a2 = wps2[0][t] + wps2[1][t] + wps2[2][t] + wps2[3][t];
        __hip_atomic_fetch_add(stats + gcol0 + t, a1,
                               __ATOMIC_RELAXED, __HIP_MEMORY_SCOPE_AGENT);
        __hip_atomic_fetch_add(stats + 8192 + gcol0 + t, a2,
                               __ATOMIC_RELAXED, __HIP_MEMORY_SCOPE_AGENT);
    }
    __syncthreads();
    if (t == 0) {
        unsigned int* fl = flags + (g * 32 + nt);
        __hip_atomic_fetch_add(fl, 1u, __ATOMIC_RELEASE, __HIP_MEMORY_SCOPE_AGENT);
        while (__hip_atomic_load(fl, __ATOMIC_ACQUIRE, __HIP_MEMORY_SCOPE_AGENT) < 2u)
            __builtin_amdgcn_s_sleep(1);
    }
    __syncthreads();
    if (t < 32) {                          // totals via atomic loads (coherent path)
        const float a1 = __hip_atomic_load(stats + gcol0 + t,
                                           __ATOMIC_RELAXED, __HIP_MEMORY_SCOPE_AGENT);
        const float a2 = __hip_atomic_load(stats + 8192 + gcol0 + t,
                                           __ATOMIC_RELAXED, __HIP_MEMORY_SCOPE_AGENT);
        const float mean = a1 * (1.0f / 256.0f);
        const float var  = a2 * (1.0f / 256.0f) - mean * mean;   // biased (jnp.var)
        const float istd = rsqrtf(var + 1e-5f);
        const float ga = gamma[gcol0 + t];
        sa[t] = ga * istd;
        sb[t] = beta[gcol0 + t] - mean * ga * istd;
    }
    __syncthreads();

    // apply affine + swish; C/D layout col=lane&15, row=(lane>>4)*4+reg
#pragma unroll
    for (int i = 0; i < 2; ++i) {
        const int row0 = h * 128 + wave * 32 + i * 16 + kq * 4;
#pragma unroll
        for (int j = 0; j < 2; ++j) {
            const int col = j * 16 + lr;
            const float a = sa[col], b2 = sb[col];
#pragma unroll
            for (int r = 0; r < 4; ++r) {
                const float z = a * acc[i][j][r] + b2;
                out[(size_t)(row0 + r) * 8192 + gcol0 + col] = z / (1.0f + expf(-z));
            }
        }
    }
}

extern "C" void kernel_launch(void* const* d_in, const int* in_sizes, int n_in,
                              void* d_out, int out_size, void* d_ws, size_t ws_size,
                              hipStream_t stream) {
    const float* x     = (const float*)d_in[0];
    const float* W     = (const float*)d_in[1];
    // d_in[2] = bias: cancelled exactly by BN mean subtraction -> unused
    const float* gamma = (const float*)d_in[3];
    const float* beta  = (const float*)d_in[4];
    // d_in[5] = mask: implicit in block structure -> unused
    float* out = (float*)d_out;

    unsigned short* xb    = (unsigned short*)d_ws;                    // 4 MB bf16 x
    float*          stats = (float*)((char*)d_ws + (4u << 20));       // 2 x 8192 f32
    unsigned int*   flags = (unsigned int*)((char*)d_ws + (4u << 20) + 65536);  // 256 u32

    // zero stats+flags every call (inside graph capture -> replay-safe)
    hipMemsetAsync((char*)d_ws + (4u << 20), 0, 65536 + 1024, stream);
    conv_kernel<<<256, 256, 0, stream>>>(x, xb);
    fused_kernel<<<512, 256, 0, stream>>>(xb, W, gamma, beta, out, stats, flags);
}

// Round 13
// 30.732 us; speedup vs baseline: 1.2223x; 1.2223x over previous
//
#include <hip/hip_runtime.h>
#include <hip/hip_bf16.h>

// DecoderBlock: block-sparse masked linear (8 GEMMs M=256,N=1024,K=1024)
// + BatchNorm1d (batch stats; bias cancels exactly) + Swish.
// Round-13: cut x re-reads. Block = 256 batch x 64 feats, K-split 2.
// grid 256 = 8g x 2kh x 16nt. x traffic 64MB (was 128), W 33.5MB once,
// bf16 col-major partials (r2-proven) -> r2's BN kernel.
// K-loop = r10's schedule: A GLL triple-ring, W reg-ring depth4 issued 3
// ahead, counted vmcnt gating only A(st+1) (16 / 12 / 0 tail).

typedef float  f32x4  __attribute__((ext_vector_type(4)));
typedef short  short8 __attribute__((ext_vector_type(8)));
typedef unsigned short u16x8 __attribute__((ext_vector_type(8)));
typedef unsigned int   u32x2 __attribute__((ext_vector_type(2)));

static __device__ __forceinline__ unsigned int f2bf(float f) {
    unsigned int u = __float_as_uint(f);
    u += 0x7FFFu + ((u >> 16) & 1u);          // RNE (inputs finite)
    return u >> 16;
}
static __device__ __forceinline__ float bf2f(unsigned short h) {
    return __uint_as_float((unsigned int)h << 16);
}

#define GLL(gp, lp) __builtin_amdgcn_global_load_lds( \
    (const __attribute__((address_space(1))) unsigned int*)(gp), \
    (__attribute__((address_space(3))) unsigned int*)(lp), 16, 0, 0)

// ---------------- x f32 -> bf16 (12 MB traffic) ----------------
__global__ __launch_bounds__(256) void conv_kernel(const float* __restrict__ x,
                                                   unsigned short* __restrict__ xb) {
    const int base = blockIdx.x * 1024 + threadIdx.x;
#pragma unroll
    for (int i = 0; i < 4; ++i) {
        const int cid = base + i * 256;               // 8-float chunk id
        const f32x4 a = *(const f32x4*)(x + (size_t)cid * 8);
        const f32x4 b = *(const f32x4*)(x + (size_t)cid * 8 + 4);
        u16x8 v;
        v[0] = f2bf(a[0]); v[1] = f2bf(a[1]); v[2] = f2bf(a[2]); v[3] = f2bf(a[3]);
        v[4] = f2bf(b[0]); v[5] = f2bf(b[1]); v[6] = f2bf(b[2]); v[7] = f2bf(b[3]);
        *(u16x8*)(xb + (size_t)cid * 8) = v;
    }
}

// ---------------- GEMM: 256x64 tile, K=512 per block (kh half) ----------------
// 4 waves M-stacked (64 rows each); acc[4][4]; 8 steps of BK=64.
// A: [256][64] bf16 LDS x3 (GLL, src pre-swizzle c^=r&7), issued 2 ahead.
// B: [64][64] bf16 LDS x2; W f32 16/thread ring depth 4, issued 3 ahead.
__global__ __launch_bounds__(256, 1) void gemm_kernel(
    const unsigned short* __restrict__ xb, const float* __restrict__ W,
    unsigned short* __restrict__ P)
{
    __shared__ __align__(16) char ldsA[3][32768];
    __shared__ __align__(16) char ldsB[2][8192];

    const int bid = blockIdx.x;
    const int g   = bid & 7;               // channel group -> XCD (round-robin)
    const int rr  = bid >> 3;
    const int kh  = rr & 1;                // K half
    const int nt  = rr >> 1;               // 0..15 (64-wide N tile)
    const int o   = g * 4 + (nt >> 2);
    const int f0  = (nt & 3) * 64;
    const int kbase = kh * 512;

    const int t    = threadIdx.x;
    const int wave = t >> 6;
    const int lane = t & 63;
    const int lr   = lane & 15;
    const int kq   = lane >> 4;

    f32x4 acc[4][4];
    const f32x4 zero = {0.f, 0.f, 0.f, 0.f};
#pragma unroll
    for (int i = 0; i < 4; ++i)
#pragma unroll
        for (int j = 0; j < 4; ++j) acc[i][j] = zero;

    f32x4 breg[4][4];                      // W ring depth 4, 16 f32/thread

    auto ISSUE_A = [&](int st) {           // 8 GLL (16B), source pre-swizzled
        const unsigned short* asrc = xb + g * 1024 + kbase + st * 64;
        char* Ab = ldsA[st % 3];
#pragma unroll
        for (int i = 0; i < 8; ++i) {
            const int cid = i * 256 + t;            // 0..2047
            const int r = cid >> 3, c = cid & 7;    // row 0..255, chunk 0..7
            GLL(asrc + (size_t)r * 8192 + (c ^ (r & 7)) * 8, Ab + cid * 16);
        }
    };
    auto ISSUE_W = [&](int st) {           // 4 x 16B: thread t -> row n=t>>2, 64B span
        const int k0 = kbase + st * 64;
        const int cp = k0 >> 8, kc = k0 & 255;
        const float* bsrc = W + ((size_t)((o * 32 + g * 4 + cp) * 256 + f0)) * 256 + kc
                              + (size_t)(t >> 2) * 256 + (t & 3) * 16;
#pragma unroll
        for (int q = 0; q < 4; ++q)
            breg[st & 3][q] = *(const f32x4*)(bsrc + q * 4);
    };
    auto WRITEB = [&](int st) {            // cvt 16 f32 -> bf16, 2 swizzled b128 writes
        const int n = t >> 2;              // 0..63
        const int c0 = (t & 3) * 2;        // 16B chunk base 0,2,4,6
        char* Bb = ldsB[st & 1];
#pragma unroll
        for (int hdx = 0; hdx < 2; ++hdx) {
            u32x2 d0, d1;
            d0[0] = f2bf(breg[st & 3][hdx * 2][0]) | (f2bf(breg[st & 3][hdx * 2][1]) << 16);
            d0[1] = f2bf(breg[st & 3][hdx * 2][2]) | (f2bf(breg[st & 3][hdx * 2][3]) << 16);
            d1[0] = f2bf(breg[st & 3][hdx * 2 + 1][0]) | (f2bf(breg[st & 3][hdx * 2 + 1][1]) << 16);
            d1[1] = f2bf(breg[st & 3][hdx * 2 + 1][2]) | (f2bf(breg[st & 3][hdx * 2 + 1][3]) << 16);
            struct { u32x2 a, b; } pack { d0, d1 };
            *(decltype(pack)*)(Bb + n * 128 + (((c0 + hdx) ^ (n & 7)) * 16)) = pack;
        }
    };
    auto COMPUTE = [&](int st) {
        const char* Ab = ldsA[st % 3];
        const char* Bb = ldsB[st & 1];
#pragma unroll
        for (int ks = 0; ks < 2; ++ks) {
            short8 af[4], bfr[4];
#pragma unroll
            for (int i = 0; i < 4; ++i) {
                const int ra = wave * 64 + i * 16 + lr;
                af[i] = *(const short8*)(Ab + ra * 128 + (((ks * 4 + kq) ^ (ra & 7)) * 16));
            }
#pragma unroll
            for (int j = 0; j < 4; ++j) {
                const int n = j * 16 + lr;
                bfr[j] = *(const short8*)(Bb + n * 128 + (((ks * 4 + kq) ^ (n & 7)) * 16));
            }
#pragma unroll
            for (int i = 0; i < 4; ++i)
#pragma unroll
                for (int j = 0; j < 4; ++j)
                    acc[i][j] = __builtin_amdgcn_mfma_f32_16x16x32_bf16(af[i], bfr[j], acc[i][j], 0, 0, 0);
        }
    };

    // prologue: A(0),A(1),W(0..2); WRITEB(0) waits W(0) (retires A(0),A(1) too).
    ISSUE_A(0);
    ISSUE_A(1);
    ISSUE_W(0);
    ISSUE_W(1);
    ISSUE_W(2);
    WRITEB(0);
    asm volatile("s_waitcnt lgkmcnt(0)" ::: "memory");
    __builtin_amdgcn_s_barrier();

#pragma unroll
    for (int st = 0; st < 8; ++st) {
        COMPUTE(st);                                   // reads A[st%3], B[st&1]
        if (st <= 5) ISSUE_A(st + 2);                  // A ring: disjoint (3-deep)
        if (st <= 4) ISSUE_W(st + 3);                  // newest vm ops: W
        if (st <= 6) {
            WRITEB(st + 1);                            // waits W(st+1) (3-iter lead)
            if (st <= 4) {
                // outstanding after wait: A(st+1)8 + W(st+2)4 + A(st+2)8 + W(st+3)4 = 24
                asm volatile("s_waitcnt vmcnt(16)" ::: "memory");  // retire A(st+1)
            } else if (st == 5) {
                // outstanding: A(6)8 + W(7)4 + A(7)8 = 20 -> retire A(6)
                asm volatile("s_waitcnt vmcnt(12)" ::: "memory");
            } else {
                asm volatile("s_waitcnt vmcnt(0)" ::: "memory");   // drain A(7)
            }
            asm volatile("s_waitcnt lgkmcnt(0)" ::: "memory");
            __builtin_amdgcn_s_barrier();
        }
    }

    // epilogue: C/D layout col=lane&15, row=(lane>>4)*4+reg.
    // Partials COL-MAJOR [8192 feat][256 batch] bf16 (r2-proven): 8B store packs 4 rows.
    unsigned short* Psp = P + (size_t)kh * 2097152;
#pragma unroll
    for (int i = 0; i < 4; ++i) {
        const int row0 = wave * 64 + i * 16 + kq * 4;
#pragma unroll
        for (int j = 0; j < 4; ++j) {
            const int gcol = o * 256 + f0 + j * 16 + lr;
            u32x2 d;
            d[0] = f2bf(acc[i][j][0]) | (f2bf(acc[i][j][1]) << 16);
            d[1] = f2bf(acc[i][j][2]) | (f2bf(acc[i][j][3]) << 16);
            *(u32x2*)(Psp + (size_t)gcol * 256 + row0) = d;
        }
    }
}

// ---------------- BN (batch stats) + Swish (r2-proven) ----------------
// 256 blocks x 32 features. Col-major partials -> 512B contiguous per feature.
__global__ __launch_bounds__(256) void bn_kernel(
    const unsigned short* __restrict__ P,
    const float* __restrict__ gamma, const float* __restrict__ beta,
    float* __restrict__ out, int s)
{
    __shared__ float ytile[256][33];
    __shared__ float ssum[32], ssq[32], sa[32], sb[32];

    const int c0 = blockIdx.x * 32;
    const int t  = threadIdx.x;
    const int cl = t >> 3, q = t & 7;    // 8 threads per feature column

    float s1 = 0.f, s2 = 0.f;
    const unsigned short* pc = P + (size_t)(c0 + cl) * 256;
#pragma unroll
    for (int p = 0; p < 4; ++p) {
        const int chunk = q + 8 * p;     // 8 rows per chunk
        float a[8];
#pragma unroll
        for (int e = 0; e < 8; ++e) a[e] = 0.f;
        for (int ksp = 0; ksp < s; ++ksp) {
            const u16x8 v = *(const u16x8*)(pc + (size_t)ksp * 2097152 + chunk * 8);
#pragma unroll
            for (int e = 0; e < 8; ++e) a[e] += bf2f(v[e]);
        }
#pragma unroll
        for (int e = 0; e < 8; ++e) {
            s1 += a[e]; s2 += a[e] * a[e];
            ytile[chunk * 8 + e][cl] = a[e];
        }
    }
    s1 += __shfl_xor(s1, 1); s2 += __shfl_xor(s2, 1);
    s1 += __shfl_xor(s1, 2); s2 += __shfl_xor(s2, 2);
    s1 += __shfl_xor(s1, 4); s2 += __shfl_xor(s2, 4);
    if (q == 0) { ssum[cl] = s1; ssq[cl] = s2; }
    __syncthreads();
    if (t < 32) {
        const float mean = ssum[t] * (1.0f / 256.0f);
        const float var  = ssq[t] * (1.0f / 256.0f) - mean * mean;   // biased (jnp.var)
        const float istd = rsqrtf(var + 1e-5f);
        const float ga = gamma[c0 + t];
        sa[t] = ga * istd;
        sb[t] = beta[c0 + t] - mean * ga * istd;
    }
    __syncthreads();
    const int rq = t >> 3, cq = q * 4;
#pragma unroll
    for (int rp = 0; rp < 8; ++rp) {
        const int r = rp * 32 + rq;
        float4 ov;
        { const float z = sa[cq+0] * ytile[r][cq+0] + sb[cq+0]; ov.x = z / (1.0f + expf(-z)); }
        { const float z = sa[cq+1] * ytile[r][cq+1] + sb[cq+1]; ov.y = z / (1.0f + expf(-z)); }
        { const float z = sa[cq+2] * ytile[r][cq+2] + sb[cq+2]; ov.z = z / (1.0f + expf(-z)); }
        { const float z = sa[cq+3] * ytile[r][cq+3] + sb[cq+3]; ov.w = z / (1.0f + expf(-z)); }
        *(float4*)(out + (size_t)r * 8192 + c0 + cq) = ov;
    }
}

extern "C" void kernel_launch(void* const* d_in, const int* in_sizes, int n_in,
                              void* d_out, int out_size, void* d_ws, size_t ws_size,
                              hipStream_t stream) {
    const float* x     = (const float*)d_in[0];
    const float* W     = (const float*)d_in[1];
    // d_in[2] = bias: cancelled exactly by BN mean subtraction -> unused
    const float* gamma = (const float*)d_in[3];
    const float* beta  = (const float*)d_in[4];
    // d_in[5] = mask: implicit in block structure -> unused
    float* out = (float*)d_out;

    unsigned short* xb = (unsigned short*)d_ws;       // 4 MB bf16 x
    unsigned short* P  = xb + 2097152;                // 2 x 4 MB bf16 partials

    conv_kernel<<<256, 256, 0, stream>>>(x, xb);
    gemm_kernel<<<256, 256, 0, stream>>>(xb, W, P);
    bn_kernel<<<256, 256, 0, stream>>>(P, gamma, beta, out, 2);
}